// Round 1
// 831.831 us; speedup vs baseline: 1.2960x; 1.2960x over previous
//
#include <hip/hip_runtime.h>
#include <hip/hip_bf16.h>
#include <cmath>

#define CCH 512
#define TLEN 8192
#define NB 8
#define KFILT 12

typedef unsigned short u16;
typedef __attribute__((ext_vector_type(8))) short short8;
typedef __attribute__((ext_vector_type(8))) unsigned short ushort8;
typedef __attribute__((ext_vector_type(4))) float float4v;
typedef __attribute__((ext_vector_type(4))) int int4v;

struct Filt { float f[KFILT]; };

// ---------- host: kaiser-sinc filter (double precision, matches numpy) ----------
static double bessel_i0(double x) {
    double sum = 1.0, term = 1.0;
    for (int k = 1; k < 40; ++k) {
        double t = (x * 0.5) / k;
        term *= t * t;
        sum += term;
        if (term < 1e-18 * sum) break;
    }
    return sum;
}

static void make_filter(float* out) {
    const int ksize = KFILT, half = KFILT / 2;
    const double cutoff = 0.5 / 2.0;
    const double half_width = 0.6 / 2.0;
    const double delta_f = 4.0 * half_width;
    const double PI = 3.14159265358979323846;
    double A = 2.285 * (half - 1) * PI * delta_f + 7.95;
    double beta;
    if (A > 50.0) beta = 0.1102 * (A - 8.7);
    else if (A >= 21.0) beta = 0.5842 * pow(A - 21.0, 0.4) + 0.07886 * (A - 21.0);
    else beta = 0.0;
    double i0b = bessel_i0(beta);
    double sum = 0.0, f[KFILT];
    for (int n = 0; n < ksize; ++n) {
        double r = (2.0 * n) / (ksize - 1) - 1.0;
        double w = bessel_i0(beta * sqrt(fmax(0.0, 1.0 - r * r))) / i0b;
        double t = (n - half) + 0.5;
        double xx = 2.0 * cutoff * t;
        double snc = (xx == 0.0) ? 1.0 : sin(PI * xx) / (PI * xx);
        f[n] = 2.0 * cutoff * w * snc;
        sum += f[n];
    }
    for (int n = 0; n < ksize; ++n) out[n] = (float)(f[n] / sum);
}

// ---------- device helpers ----------
__device__ __forceinline__ float bf2f(u16 u) {
    return __uint_as_float(((unsigned int)u) << 16);
}
__device__ __forceinline__ u16 f2bf(float f) {
    unsigned int x = __float_as_uint(f);
    unsigned int r = (x + 0x7fffu + ((x >> 16) & 1u)) >> 16;
    return (u16)r;
}
__device__ __forceinline__ float ldin(const void* p, size_t i, int isf) {
    return isf ? ((const float*)p)[i] : bf2f(((const u16*)p)[i]);
}
__device__ __forceinline__ void gl_lds16(const void* g, void* s) {
    __builtin_amdgcn_global_load_lds(
        (const __attribute__((address_space(1))) unsigned int*)g,
        (__attribute__((address_space(3))) unsigned int*)s, 16, 0, 0);
}

// ---------- dtype sniffer: bf16-view of f32 data has wild exponents ----------
__global__ __launch_bounds__(256) void k_detect(const u16* __restrict__ x,
                                                int* __restrict__ flag) {
    int tid = threadIdx.x;
    int bad = 0;
    for (int i = tid; i < 4096; i += 256) {
        int e = (x[i] >> 7) & 0xFF;
        if (e >= 0x86) bad++;   // |v| >= 64 or inf/nan as bf16
    }
    for (int off = 32; off > 0; off >>= 1) bad += __shfl_down(bad, off, 64);
    __shared__ int r[4];
    if ((tid & 63) == 0) r[tid >> 6] = bad;
    __syncthreads();
    if (tid == 0) flag[0] = (r[0] + r[1] + r[2] + r[3] >= 64) ? 1 : 0;
}

// ---------- per-out-channel weight-norm scale: g / ||v|| ----------
__global__ __launch_bounds__(256) void k_scales(const void* __restrict__ v,
                                                const void* __restrict__ g,
                                                float* __restrict__ scales,
                                                const int* __restrict__ flg) {
    int isf = *flg;
    int blk = blockIdx.x;            // [0, 3*512)
    int tid = threadIdx.x;
    float s = 0.f;
    for (int i = tid; i < CCH * 3; i += 256) {
        float x = ldin(v, (size_t)blk * (CCH * 3) + i, isf);
        s = fmaf(x, x, s);
    }
    for (int off = 32; off > 0; off >>= 1) s += __shfl_down(s, off, 64);
    __shared__ float red[4];
    if ((tid & 63) == 0) red[tid >> 6] = s;
    __syncthreads();
    if (tid == 0) {
        float tot = red[0] + red[1] + red[2] + red[3];
        scales[blk] = ldin(g, blk, isf) / sqrtf(tot);
    }
}

// ---------- repack weights: Wp[l][tap][co][ci] = v[l][co][ci][tap] (bf16) ----------
__global__ __launch_bounds__(256) void k_repack(const void* __restrict__ v,
                                                u16* __restrict__ wp,
                                                const int* __restrict__ flg) {
    int isf = *flg;
    int l = blockIdx.y;
    int i = blockIdx.x * 256 + threadIdx.x;   // < 3*512*512
    int tap = i >> 18;
    int rem = i & 262143;
    int co = rem >> 9, ci = rem & 511;
    size_t src = (((size_t)l * CCH + co) * CCH + ci) * 3 + tap;
    u16 val = isf ? f2bf(((const float*)v)[src]) : ((const u16*)v)[src];
    wp[(((size_t)l * 3 + tap) * CCH + co) * CCH + ci] = val;
}

// ---------- upsample+snake value generator, all indices compile-time ----------
// su(u_local) for u = 2*t0 + UL (t0 = thread's first output t):
//   s = floor(u/2); odd u: sum F[2r+1]*x[s+r-2]; even u: sum F[2r]*x[s+r-3]; *2; snake.
// xr[k] = x[clamp(t0-6+k)] so x index s+r-2 -> k = S+r+4 (odd), s+r-3 -> k = S+r+3.
template<int UL>
__device__ __forceinline__ float su_val(const float* xr, const Filt& F,
                                        float a, float invb) {
    constexpr int S = (UL < 0) ? -(((-UL) + 1) / 2) : (UL / 2);   // floor(UL/2)
    constexpr int P = ((UL % 2) + 2) % 2;                          // parity
    constexpr int B = S + (P ? 4 : 3);                             // xr base idx
    float acc = F.f[P] * xr[B];
    #pragma unroll
    for (int r = 1; r < 6; ++r) acc = fmaf(F.f[2 * r + P], xr[B + r], acc);
    acc *= 2.0f;
    float sn = __sinf(acc * a);
    return fmaf(invb, sn * sn, acc);
}

// ---------- fused activation1d: all-register streaming (zero LDS) ----------
// Previous version moved every intermediate through LDS with scalar ds ops
// (~400 b32 LDS ops/thread ~ 120us of LDS-pipe serialization). This version:
// one thread = one channel x 32 consecutive outputs; 44-value x window in
// registers (vector loads); 12-slot rolling window of snake(up) values with
// compile-time indices; 12-tap downsample in registers. Writes coalesce as
// 64 lanes x contiguous c (128B/store).
__global__ __launch_bounds__(256) void k_act(const void* __restrict__ xsrc,
                                             const void* __restrict__ alpha,
                                             const void* __restrict__ beta,
                                             int prmofs, u16* __restrict__ xt,
                                             Filt F, const int* __restrict__ flg,
                                             int layer0) {
    const int isf = *flg;
    const int sif = layer0 ? isf : 0;   // carrier is always bf16 after layer 0
    const int tid = threadIdx.x;
    const int lane = tid & 63, w = tid >> 6;
    const int b = blockIdx.z;
    const int c = blockIdx.y * 64 + lane;
    const int t0 = blockIdx.x * 128 + w * 32;        // wave-uniform
    const size_t rowbase = ((size_t)(b * CCH + c)) * TLEN;

    const float a = expf(ldin(alpha, prmofs + c, isf));
    const float invb = 1.0f / (expf(ldin(beta, prmofs + c, isf)) + 1e-9f);

    // ---- x window: xr[k] = x[clamp(t0-6+k)], k in [0,44) ----
    float xr[44];
    const bool interior = (t0 != 0) && (t0 != TLEN - 32);   // wave-uniform
    if (sif) {
        const float* xp = (const float*)xsrc + rowbase;
        if (interior) {
            #pragma unroll
            for (int i = 0; i < 12; ++i) {
                float4v v = *(const float4v*)(xp + t0 - 8 + i * 4);
                #pragma unroll
                for (int j = 0; j < 4; ++j) {
                    int k = i * 4 + j - 2;
                    if (k >= 0 && k < 44) xr[k] = v[j];
                }
            }
        } else {
            #pragma unroll
            for (int k = 0; k < 44; ++k)
                xr[k] = xp[min(max(t0 - 6 + k, 0), TLEN - 1)];
        }
    } else {
        const u16* xp = (const u16*)xsrc + rowbase;
        if (interior) {
            #pragma unroll
            for (int i = 0; i < 6; ++i) {
                ushort8 v = *(const ushort8*)(xp + t0 - 8 + i * 8);
                #pragma unroll
                for (int j = 0; j < 8; ++j) {
                    int k = i * 8 + j - 2;
                    if (k >= 0 && k < 44) xr[k] = bf2f(v[j]);
                }
            }
        } else {
            #pragma unroll
            for (int k = 0; k < 44; ++k)
                xr[k] = bf2f(xp[min(max(t0 - 6 + k, 0), TLEN - 1)]);
        }
    }

    // ---- init rolling window: slots for u_local = -5..6, slot(u) = u mod 12 ----
    float wv[12];
    wv[7]  = su_val<-5>(xr, F, a, invb);
    wv[8]  = su_val<-4>(xr, F, a, invb);
    wv[9]  = su_val<-3>(xr, F, a, invb);
    wv[10] = su_val<-2>(xr, F, a, invb);
    wv[11] = su_val<-1>(xr, F, a, invb);
    wv[0]  = su_val<0>(xr, F, a, invb);
    wv[1]  = su_val<1>(xr, F, a, invb);
    wv[2]  = su_val<2>(xr, F, a, invb);
    wv[3]  = su_val<3>(xr, F, a, invb);
    wv[4]  = su_val<4>(xr, F, a, invb);
    wv[5]  = su_val<5>(xr, F, a, invb);
    wv[6]  = su_val<6>(xr, F, a, invb);
    // left edge: u<0 clamps to u=0 (edge-replicate of snake output)
    if (t0 == 0) { wv[7] = wv[8] = wv[9] = wv[10] = wv[11] = wv[0]; }
    // right edge: u>2T-1 clamps to u=2T-1 (odd, u_local=63 at the last thread)
    const bool right = (t0 == TLEN - 32);
    const float su_hi = su_val<63>(xr, F, a, invb);

    u16* orow = xt + (size_t)b * TLEN * CCH + c;

#define IDXW(u) ((((u) % 12) + 12) % 12)
#define ACT_STEP(TL) { \
      float acc = F.f[0] * wv[IDXW(2*(TL)-5)]; \
      acc = fmaf(F.f[1],  wv[IDXW(2*(TL)-4)], acc); \
      acc = fmaf(F.f[2],  wv[IDXW(2*(TL)-3)], acc); \
      acc = fmaf(F.f[3],  wv[IDXW(2*(TL)-2)], acc); \
      acc = fmaf(F.f[4],  wv[IDXW(2*(TL)-1)], acc); \
      acc = fmaf(F.f[5],  wv[IDXW(2*(TL)+0)], acc); \
      acc = fmaf(F.f[6],  wv[IDXW(2*(TL)+1)], acc); \
      acc = fmaf(F.f[7],  wv[IDXW(2*(TL)+2)], acc); \
      acc = fmaf(F.f[8],  wv[IDXW(2*(TL)+3)], acc); \
      acc = fmaf(F.f[9],  wv[IDXW(2*(TL)+4)], acc); \
      acc = fmaf(F.f[10], wv[IDXW(2*(TL)+5)], acc); \
      acc = fmaf(F.f[11], wv[IDXW(2*(TL)+6)], acc); \
      orow[(size_t)(t0 + (TL)) * CCH] = f2bf(acc); \
      if ((TL) < 31) { \
        float nv1 = su_val<2*(TL)+7>(xr, F, a, invb); \
        float nv2 = su_val<2*(TL)+8>(xr, F, a, invb); \
        if ((2*(TL)+7) > 63) nv1 = right ? su_hi : nv1; \
        if ((2*(TL)+8) > 63) nv2 = right ? su_hi : nv2; \
        wv[IDXW(2*(TL)+7)] = nv1; \
        wv[IDXW(2*(TL)+8)] = nv2; \
      } \
    }

    ACT_STEP(0)  ACT_STEP(1)  ACT_STEP(2)  ACT_STEP(3)
    ACT_STEP(4)  ACT_STEP(5)  ACT_STEP(6)  ACT_STEP(7)
    ACT_STEP(8)  ACT_STEP(9)  ACT_STEP(10) ACT_STEP(11)
    ACT_STEP(12) ACT_STEP(13) ACT_STEP(14) ACT_STEP(15)
    ACT_STEP(16) ACT_STEP(17) ACT_STEP(18) ACT_STEP(19)
    ACT_STEP(20) ACT_STEP(21) ACT_STEP(22) ACT_STEP(23)
    ACT_STEP(24) ACT_STEP(25) ACT_STEP(26) ACT_STEP(27)
    ACT_STEP(28) ACT_STEP(29) ACT_STEP(30) ACT_STEP(31)
#undef ACT_STEP
#undef IDXW
}

// ---------- wn_conv (k=3 dilated) as MFMA implicit GEMM + residual ----------
// 2-phase double-buffered pipeline (T3-minimum): stage ci-step s+1 while
// doing MFMA on step s; ONE __syncthreads per step (its vmcnt(0) drain is the
// prefetch landing point — the prefetch had the whole ds_read+MFMA phase in
// flight). LDS: A dbuf 2x24576 + X dbuf 2x12288 = 73728 B (dynamic, >64KB
// via hipFuncSetAttribute) -> 2 blocks/CU.
__global__ __launch_bounds__(256) void k_conv(const u16* __restrict__ xt,
                                              const u16* __restrict__ wp,
                                              const float* __restrict__ scales,
                                              const void* __restrict__ bias,
                                              int bofs,
                                              const void* __restrict__ rsrc,
                                              int layer0,
                                              u16* __restrict__ wdst,
                                              void* __restrict__ outp, int d,
                                              const int* __restrict__ flg) {
    extern __shared__ char smem[];
    // layout: A0 [0,24576) A1 [24576,49152) X0 [49152,61440) X1 [61440,73728)
    const int isf = *flg;
    const int rif = layer0 ? isf : 0;
    const int tid = threadIdx.x;
    const int lane = tid & 63, wid = tid >> 6;
    const int wm = wid & 1, wn = wid >> 1;
    const int b = blockIdx.z, co0 = blockIdx.y * 128, t0 = blockIdx.x * 128;
    const int q = lane >> 4, l15 = lane & 15;
    const int nX = (128 + 2 * d) * 4;              // live X granules
    const bool edge = (t0 == 0) || (t0 + 128 == TLEN);
    const u16* xtb = xt + (size_t)b * TLEN * CCH;

    float4v acc[4][4];
    #pragma unroll
    for (int i = 0; i < 4; ++i)
        #pragma unroll
        for (int j = 0; j < 4; ++j) acc[i][j] = (float4v){0.f, 0.f, 0.f, 0.f};

    // ---- staging helpers (XOR-swizzled granules, full waves) ----
    auto stageA = [&](int ci0, char* As) {
        #pragma unroll
        for (int i = 0; i < 6; ++i) {
            int base = (i * 4 + wid) * 64;
            int L = base + lane;
            int tap = L >> 9;
            int co = (L >> 2) & 127;
            int g = (L & 3) ^ ((co >> 1) & 3);
            gl_lds16(wp + (((size_t)tap * CCH + co0 + co) * CCH + ci0 + g * 8),
                     As + base * 16);
        }
    };
    auto stageX = [&](int ci0, char* Xs) {
        #pragma unroll
        for (int i = 0; i < 3; ++i) {
            int base = (i * 4 + wid) * 64;
            int L = base + lane;
            int t = L >> 2;
            int g = (L & 3) ^ ((t >> 1) & 3);
            int tg = min(max(t0 - d + t, 0), TLEN - 1);
            gl_lds16(xtb + ((size_t)tg * CCH + ci0 + g * 8), Xs + base * 16);
        }
    };
    auto fixX = [&](char* Xs) {   // zero out-of-range rows (conv zero-pad)
        for (int j = tid; j < nX; j += 256) {
            int tg = t0 - d + (j >> 2);
            if (tg < 0 || tg >= TLEN)
                *(int4v*)(Xs + (size_t)j * 16) = (int4v){0, 0, 0, 0};
        }
    };

    // ---- prologue: stage step 0 ----
    stageA(0, smem);
    stageX(0, smem + 49152);
    __syncthreads();                       // vmcnt(0) drain + barrier
    if (edge) { fixX(smem + 49152); __syncthreads(); }

    // ---- main loop: prefetch s+1 || compute s; one barrier per step ----
    #pragma unroll 2
    for (int s = 0; s < 16; ++s) {
        const int cur = s & 1, nxt = cur ^ 1;
        char* As = smem + cur * 24576;
        char* Xs = smem + 49152 + cur * 12288;
        if (s < 15) {                      // issue BEFORE compute (T3)
            stageA((s + 1) * 32, smem + nxt * 24576);
            stageX((s + 1) * 32, smem + 49152 + nxt * 12288);
        }
        #pragma unroll
        for (int tap = 0; tap < 3; ++tap) {
            short8 af[4], bfr[4];
            #pragma unroll
            for (int mi = 0; mi < 4; ++mi) {
                int co = wm * 64 + mi * 16 + l15;
                af[mi] = *(const short8*)(As + tap * 8192 + co * 64 +
                                          ((q ^ ((co >> 1) & 3)) * 16));
            }
            #pragma unroll
            for (int ni = 0; ni < 4; ++ni) {
                int r = wn * 64 + ni * 16 + l15 + tap * d;
                bfr[ni] = *(const short8*)(Xs + r * 64 + ((q ^ ((r >> 1) & 3)) * 16));
            }
            #pragma unroll
            for (int mi = 0; mi < 4; ++mi)
                #pragma unroll
                for (int ni = 0; ni < 4; ++ni)
                    acc[mi][ni] = __builtin_amdgcn_mfma_f32_16x16x32_bf16(
                        af[mi], bfr[ni], acc[mi][ni], 0, 0, 0);
        }
        __syncthreads();                   // drains prefetch + WAR guard
        if (edge && s < 15) {
            fixX(smem + 49152 + nxt * 12288);
            __syncthreads();
        }
    }

    // ---- epilogue: y = scale*acc + bias + residual ----
    float scl[4][4], bia[4][4];
    #pragma unroll
    for (int mi = 0; mi < 4; ++mi)
        #pragma unroll
        for (int rg = 0; rg < 4; ++rg) {
            int co = co0 + wm * 64 + mi * 16 + q * 4 + rg;
            scl[mi][rg] = scales[co];
            bia[mi][rg] = ldin(bias, bofs + co, isf);
        }
    #pragma unroll
    for (int mi = 0; mi < 4; ++mi)
        #pragma unroll
        for (int ni = 0; ni < 4; ++ni) {
            int tg = t0 + wn * 64 + ni * 16 + l15;
            #pragma unroll
            for (int rg = 0; rg < 4; ++rg) {
                int co = co0 + wm * 64 + mi * 16 + q * 4 + rg;
                size_t idx = ((size_t)(b * CCH + co)) * TLEN + tg;
                float resid = rif ? ((const float*)rsrc)[idx]
                                  : bf2f(((const u16*)rsrc)[idx]);
                float val = fmaf(acc[mi][ni][rg], scl[mi][rg], bia[mi][rg]) + resid;
                if (wdst) {
                    wdst[idx] = f2bf(val);
                } else {
                    if (isf) ((float*)outp)[idx] = val;
                    else ((u16*)outp)[idx] = f2bf(val);
                }
            }
        }
}

// ---------- launcher ----------
extern "C" void kernel_launch(void* const* d_in, const int* in_sizes, int n_in,
                              void* d_out, int out_size, void* d_ws, size_t ws_size,
                              hipStream_t stream) {
    const void* x_in  = d_in[0];
    const void* v_in  = d_in[1];
    const void* g_in  = d_in[2];
    const void* b_in  = d_in[3];
    const void* al_in = d_in[4];
    const void* be_in = d_in[5];

    char* ws = (char*)d_ws;
    u16*   xc     = (u16*)ws;                                     // 67108864 B
    u16*   xt     = (u16*)(ws + 67108864);                        // 67108864 B
    u16*   wp     = (u16*)(ws + 134217728);                       // 4718592 B
    float* scales = (float*)(ws + 134217728 + 4718592);           // 6144 B
    int*   flag   = (int*)(ws + 134217728 + 4718592 + 6144);

    Filt F;
    make_filter(F.f);

    // allow 73728 B dynamic LDS for k_conv (host-side attr, capture-safe)
    (void)hipFuncSetAttribute((const void*)k_conv,
                              hipFuncAttributeMaxDynamicSharedMemorySize, 73728);

    k_detect<<<1, 256, 0, stream>>>((const u16*)x_in, flag);
    k_scales<<<3 * CCH, 256, 0, stream>>>(v_in, g_in, scales, flag);
    k_repack<<<dim3(3072, 3), 256, 0, stream>>>(v_in, wp, flag);

    const int dil[3] = {1, 3, 5};
    for (int l = 0; l < 3; ++l) {
        const void* src = (l == 0) ? x_in : (const void*)xc;
        k_act<<<dim3(TLEN / 128, CCH / 64, NB), 256, 0, stream>>>(
            src, al_in, be_in, l * CCH, xt, F, flag, (l == 0) ? 1 : 0);
        k_conv<<<dim3(TLEN / 128, CCH / 128, NB), 256, 73728, stream>>>(
            xt, wp + (size_t)l * 3 * CCH * CCH, scales + l * CCH, b_in, l * CCH,
            src, (l == 0) ? 1 : 0,
            (l == 2) ? (u16*)nullptr : xc,
            (l == 2) ? d_out : nullptr, dil[l], flag);
    }
}